// Round 2
// baseline (12262.378 us; speedup 1.0000x reference)
//
#include <hip/hip_runtime.h>
#include <cstddef>

#define Hd 51
#define Td 2048
#define BBd 4
#define NT 704
#define NBLK 256

__device__ __forceinline__ float fast_rcp(float x) {
#if __has_builtin(__builtin_amdgcn_rcpf)
    return __builtin_amdgcn_rcpf(x);
#else
    return 1.0f / x;
#endif
}

// ag=1,bg=0 -> sigmoid(a); ag=2,bg=-1 -> tanh(a) (tanh(a)=2*sigmoid(2a)-1)
__device__ __forceinline__ float gate_act(float a, float ag, float bg) {
    float e = __expf(-a * ag);
    float s = fast_rcp(1.0f + e);
    return fmaf(s, ag, bg);
}

__device__ __forceinline__ float tanh_fast(float x) {
    float e = __expf(-2.0f * fabsf(x));
    float t = (1.0f - e) * fast_rcp(1.0f + e);
    return copysignf(t, x);
}

// Thread roles within the 704-thread block (11 waves):
//   tid [0,204)    : layer-0 gate rows (row j = tid), 2+51 MACs
//   tid [204,212)  : output head: (col = (tid-204)>>2, b = (tid-204)&3)
//   tid [212,220)  : x prefetch: (feat = (tid-212)>>2, b = (tid-212)&3)
//   tid [256,664)  : heavy gate rows: hr=tid-256, layer = 1+hr/204, row = hr%204
//   rest           : idle (barrier only)
// Wave->SIMD (i%4): S0..S2 = {L0, heavy, heavy} ~2810cyc, S3 = {mixed, heavy}.
__global__ __launch_bounds__(NT, 3)
void lstm3_kernel(const float* __restrict__ g_input,
                  const float* __restrict__ g_time,
                  const float* __restrict__ Wih0, const float* __restrict__ Whh0,
                  const float* __restrict__ bih0, const float* __restrict__ bhh0,
                  const float* __restrict__ Wih1, const float* __restrict__ Whh1,
                  const float* __restrict__ bih1, const float* __restrict__ bhh1,
                  const float* __restrict__ Wih2, const float* __restrict__ Whh2,
                  const float* __restrict__ bih2, const float* __restrict__ bhh2,
                  const float* __restrict__ Wlin, const float* __restrict__ blin,
                  float* __restrict__ g_out)
{
    __shared__ float sh_h[3][2][Hd][BBd];   // double-buffered hidden states
    __shared__ float sh_g[3][4 * Hd][BBd];  // activated gates (i,f,g,o rows)
    __shared__ float sh_x[2][2][BBd];       // double-buffered x (input,time)

    const int tid = threadIdx.x;
    const int b0 = blockIdx.x * BBd;

    int role = 3;          // 0=gate-row, 1=out-head, 2=prefetch, 3=idle
    int lay = 0, row = 0;
    if (tid < 204)                      { role = 0; lay = 0; row = tid; }
    else if (tid < 212)                 { role = 1; }
    else if (tid < 220)                 { role = 2; }
    else if (tid >= 256 && tid < 664)   { role = 0; int hr = tid - 256; lay = 1 + hr / 204; row = hr % 204; }

    const int o_idx  = tid - 204;
    const int o_col  = (o_idx >> 2) & 1;
    const int o_b    = o_idx & 3;
    const int p_idx  = tid - 212;
    const int p_feat = (p_idx >> 2) & 1;
    const int p_b    = p_idx & 3;

    float wih[Hd];
    float whh[Hd];
    float bias = 0.0f;

    if (role == 0) {
        const float* Wih = (lay == 0) ? Wih0 : ((lay == 1) ? Wih1 : Wih2);
        const float* Whh = (lay == 0) ? Whh0 : ((lay == 1) ? Whh1 : Whh2);
        const float* bih = (lay == 0) ? bih0 : ((lay == 1) ? bih1 : bih2);
        const float* bhh = (lay == 0) ? bhh0 : ((lay == 1) ? bhh1 : bhh2);
        bias = bih[row] + bhh[row];
        #pragma unroll
        for (int k = 0; k < Hd; ++k) whh[k] = Whh[row * Hd + k];
        if (lay == 0) {
            wih[0] = Wih[row * 2 + 0];
            wih[1] = Wih[row * 2 + 1];
        } else {
            #pragma unroll
            for (int k = 0; k < Hd; ++k) wih[k] = Wih[row * Hd + k];
        }
    } else if (role == 1) {
        #pragma unroll
        for (int k = 0; k < Hd; ++k) whh[k] = Wlin[o_col * Hd + k];
        bias = blin[o_col];
    }

    // gate nonlinearity params: rows [2H,3H) are 'g' -> tanh, else sigmoid
    const bool  isg = (row >= 2 * Hd) && (row < 3 * Hd);
    const float ag  = isg ? 2.0f : 1.0f;
    const float bg  = isg ? -1.0f : 0.0f;

    // phase-2 mapping: tid < 612 -> (layer, elem, batch); c lives here
    const int p2l = tid / 204;
    const int p2r = tid % 204;
    const int p2e = p2r >> 2;
    const int p2b = p2r & 3;
    float c_state = 0.0f;

    // zero both h buffers (initial state, and pre-first-write reads)
    for (int i = tid; i < 3 * 2 * Hd * BBd; i += NT) ((float*)sh_h)[i] = 0.0f;

    // prologue: x(t=0) -> sh_x[1]  (rb at it=0 is 1)
    if (role == 2) {
        const float* src = (p_feat == 0) ? g_input : g_time;
        sh_x[1][p_feat][p_b] = src[(size_t)(b0 + p_b) * Td];
    }
    __syncthreads();

    const float* hin_base  = (role == 0 && lay > 0) ? &sh_h[lay - 1][0][0][0] : (const float*)&sh_h[0][0][0][0];
    const float* hown_base = &sh_h[lay][0][0][0];

    for (int it = 0; it < Td + 3; ++it) {
        const int rb = (it & 1) ^ 1;
        const int wb = it & 1;

        // prefetch next x into register (written to LDS after barrier 1)
        float pfv = 0.0f;
        if (role == 2 && (it + 1) < Td) {
            const float* src = (p_feat == 0) ? g_input : g_time;
            pfv = src[(size_t)(b0 + p_b) * Td + (it + 1)];
        }

        if (role == 0) {
            const int tl = it - lay;
            if (tl >= 0 && tl < Td) {
                float a0 = bias, a1 = bias, a2 = bias, a3 = bias;
                if (lay == 0) {
                    const float4 x0 = *(const float4*)&sh_x[rb][0][0];
                    const float4 x1 = *(const float4*)&sh_x[rb][1][0];
                    a0 = fmaf(wih[0], x0.x, a0); a1 = fmaf(wih[0], x0.y, a1);
                    a2 = fmaf(wih[0], x0.z, a2); a3 = fmaf(wih[0], x0.w, a3);
                    a0 = fmaf(wih[1], x1.x, a0); a1 = fmaf(wih[1], x1.y, a1);
                    a2 = fmaf(wih[1], x1.z, a2); a3 = fmaf(wih[1], x1.w, a3);
                } else {
                    const float* hin = hin_base + rb * (Hd * BBd);
                    #pragma unroll
                    for (int k = 0; k < Hd; ++k) {
                        const float4 hv = *(const float4*)(hin + k * BBd);
                        a0 = fmaf(wih[k], hv.x, a0); a1 = fmaf(wih[k], hv.y, a1);
                        a2 = fmaf(wih[k], hv.z, a2); a3 = fmaf(wih[k], hv.w, a3);
                    }
                }
                {
                    const float* hw = hown_base + rb * (Hd * BBd);
                    #pragma unroll
                    for (int k = 0; k < Hd; ++k) {
                        const float4 hv = *(const float4*)(hw + k * BBd);
                        a0 = fmaf(whh[k], hv.x, a0); a1 = fmaf(whh[k], hv.y, a1);
                        a2 = fmaf(whh[k], hv.z, a2); a3 = fmaf(whh[k], hv.w, a3);
                    }
                }
                float4 gv;
                gv.x = gate_act(a0, ag, bg);
                gv.y = gate_act(a1, ag, bg);
                gv.z = gate_act(a2, ag, bg);
                gv.w = gate_act(a3, ag, bg);
                *(float4*)&sh_g[lay][row][0] = gv;
            }
        } else if (role == 1) {
            const int to = it - 3;
            if (to >= 0 && to < Td) {
                float a = bias;
                #pragma unroll
                for (int k = 0; k < Hd; ++k)
                    a = fmaf(whh[k], sh_h[2][rb][k][o_b], a);
                if (o_col == 1) {
                    // softplus with the reference's inf guard
                    a = (a > 30.0f) ? a : __logf(1.0f + __expf(a));
                }
                g_out[((size_t)(b0 + o_b) * Td + to) * 2 + o_col] = a;
            }
        }

        __syncthreads();   // gates visible

        if (tid < 612) {
            const int t2 = it - p2l;
            if (t2 >= 0 && t2 < Td) {
                const float gi = sh_g[p2l][p2e][p2b];
                const float gf = sh_g[p2l][Hd + p2e][p2b];
                const float gg = sh_g[p2l][2 * Hd + p2e][p2b];
                const float go = sh_g[p2l][3 * Hd + p2e][p2b];
                c_state = fmaf(gf, c_state, gi * gg);
                sh_h[p2l][wb][p2e][p2b] = go * tanh_fast(c_state);
            }
        }
        if (role == 2 && (it + 1) < Td) {
            sh_x[wb][p_feat][p_b] = pfv;
        }
        __syncthreads();   // h / x visible for next iteration
    }
}

extern "C" void kernel_launch(void* const* d_in, const int* in_sizes, int n_in,
                              void* d_out, int out_size, void* d_ws, size_t ws_size,
                              hipStream_t stream) {
    const float* input = (const float*)d_in[0];
    const float* timei = (const float*)d_in[1];
    const float* Wih0  = (const float*)d_in[2];
    const float* Whh0  = (const float*)d_in[3];
    const float* bih0  = (const float*)d_in[4];
    const float* bhh0  = (const float*)d_in[5];
    const float* Wih1  = (const float*)d_in[6];
    const float* Whh1  = (const float*)d_in[7];
    const float* bih1  = (const float*)d_in[8];
    const float* bhh1  = (const float*)d_in[9];
    const float* Wih2  = (const float*)d_in[10];
    const float* Whh2  = (const float*)d_in[11];
    const float* bih2  = (const float*)d_in[12];
    const float* bhh2  = (const float*)d_in[13];
    const float* Wlin  = (const float*)d_in[14];
    const float* blin  = (const float*)d_in[15];
    float* out = (float*)d_out;

    lstm3_kernel<<<dim3(NBLK), dim3(NT), 0, stream>>>(
        input, timei,
        Wih0, Whh0, bih0, bhh0,
        Wih1, Whh1, bih1, bhh1,
        Wih2, Whh2, bih2, bhh2,
        Wlin, blin, out);
}

// Round 4
// 2970.922 us; speedup vs baseline: 4.1275x; 4.1275x over previous
//
#include <hip/hip_runtime.h>
#include <cstddef>
#include <cstdint>

#define Hd 51
#define Td 2048
#define NBb 16      // batches per block
#define NTH 512     // 8 waves
#define NBLK 64

typedef _Float16 f16x8 __attribute__((ext_vector_type(8)));
typedef _Float16 f16x4 __attribute__((ext_vector_type(4)));
typedef float    f32x4 __attribute__((ext_vector_type(4)));

// LDS: per buffer, 4 panels indexed (db*2+part): part0 = hi f16, part1 = lo f16.
//  buf0: rows 128 B, k: [h0 0..50][pad][x 52,53][one 54][pad..63]
//  buf1: rows 256 B, k: [h0 0..50][pad][h1 56..106][pad][one 112][pad..127]
//  buf2: rows 256 B, k: [h1 0..50][pad][h2 56..106][pad][one 112][pad..127]
#define RB0   128
#define RB12  256
#define BASE0 0
#define BASE1 8192
#define BASE2 24576
#define LDSB  40960

__device__ __forceinline__ int vaddr(int base, int rowB, int db, int part, int n, int off) {
    // XOR swizzle spreads the 16 batch-rows across banks for b128 column reads
    return base + ((db * 2 + part) * NBb + n) * rowB + (off ^ ((n & 7) << 4));
}

__device__ __forceinline__ float fast_rcp(float x) { return __builtin_amdgcn_rcpf(x); }
__device__ __forceinline__ float sigm(float x) { return fast_rcp(1.f + __expf(-x)); }
__device__ __forceinline__ float tanh_g(float x) { return fmaf(2.f, fast_rcp(1.f + __expf(-2.f * x)), -1.f); }
__device__ __forceinline__ float tanh_c(float x) {
    float e = __expf(-2.f * fabsf(x));
    float t = (1.f - e) * fast_rcp(1.f + e);
    return copysignf(t, x);
}

// i,f,g,o -> c,h update; writes h as hi+lo f16 pair into 1 or 2 buffers.
// lo panel of a buffer sits +NBb*rowB bytes after the hi panel.
__device__ __forceinline__ void update_write(unsigned char* lds, const f32x4* acc,
                                             float (&cs)[4], int aH1, int rB1,
                                             int aH2, int rB2) {
    f16x4 hH, hL;
    #pragma unroll
    for (int r = 0; r < 4; ++r) {
        float gi = sigm(acc[0][r]);
        float gf = sigm(acc[1][r]);
        float gg = tanh_g(acc[2][r]);
        float go = sigm(acc[3][r]);
        float cn = fmaf(gf, cs[r], gi * gg);
        cs[r] = cn;
        float h  = go * tanh_c(cn);
        _Float16 hi = (_Float16)h;
        hH[r] = hi;
        hL[r] = (_Float16)(h - (float)hi);
    }
    *(f16x4*)(lds + aH1) = hH;
    *(f16x4*)(lds + aH1 + NBb * rB1) = hL;
    if (aH2 >= 0) {
        *(f16x4*)(lds + aH2) = hH;
        *(f16x4*)(lds + aH2 + NBb * rB2) = hL;
    }
}

__global__ __launch_bounds__(NTH, 2)
void lstm3_mfma(const float* __restrict__ g_input, const float* __restrict__ g_time,
                const float* __restrict__ Wih0, const float* __restrict__ Whh0,
                const float* __restrict__ bih0, const float* __restrict__ bhh0,
                const float* __restrict__ Wih1, const float* __restrict__ Whh1,
                const float* __restrict__ bih1, const float* __restrict__ bhh1,
                const float* __restrict__ Wih2, const float* __restrict__ Whh2,
                const float* __restrict__ bih2, const float* __restrict__ bhh2,
                const float* __restrict__ Wlin, const float* __restrict__ blin,
                float* __restrict__ g_out)
{
    __shared__ __align__(16) unsigned char lds[LDSB];

    const int tid  = threadIdx.x;
    const int lane = tid & 63;
    const int w    = tid >> 6;       // wave 0..7
    const int c    = w & 3;          // element-chunk (16 elements)
    const bool low = (w < 4);        // low waves: L0+L1 ; high waves: L2+head
    const int ncol = lane & 15;      // batch col (B) / A-row-in-tile
    const int kg   = lane >> 4;      // k-group 0..3
    const int b0   = blockIdx.x * NBb;

    // ---- zero LDS ----
    for (int i = tid * 4; i < LDSB; i += NTH * 4) *(uint32_t*)(lds + i) = 0u;
    __syncthreads();

    // one-slots (bias column of B, hi panels only) in BOTH double buffers; x(t=0)
    if (tid < 32) {
        int db = tid >> 4, n = tid & 15;
        *(unsigned short*)(lds + vaddr(BASE0, RB0,  db, 0, n,  54 * 2)) = 0x3C00; // f16 1.0
        *(unsigned short*)(lds + vaddr(BASE1, RB12, db, 0, n, 112 * 2)) = 0x3C00;
        *(unsigned short*)(lds + vaddr(BASE2, RB12, db, 0, n, 112 * 2)) = 0x3C00;
    } else if (tid >= 64 && tid < 96) {
        int i = tid - 64; int n = i & 15, f = i >> 4;
        const float* src = f ? g_time : g_input;
        float v = src[(size_t)(b0 + n) * Td];
        _Float16 hi = (_Float16)v;
        *(_Float16*)(lds + vaddr(BASE0, RB0, 0, 0, n, (52 + f) * 2)) = hi;
        *(_Float16*)(lds + vaddr(BASE0, RB0, 0, 1, n, (52 + f) * 2)) = (_Float16)(v - (float)hi);
    }

    // ---- load weight A-fragments (f16 hi only) ----
    // A-frag lane map (16x16x32): row = 16*tile + (lane&15), k = 32*s + 8*(lane>>4) + e
    // wave owns tiles {c, c+4, c+8, c+12}: gate gs rows = 64*gs + er, er = 16c + ncol
    const int er = 16 * c + ncol;
    const bool rvalid = (er < Hd);
    f16x8 AF[24];   // low: [0..7]=L0 (4 gates x 2 ksteps), [8..23]=L1 ; high: [0..15]=L2

    if (low) {
        #pragma unroll
        for (int gs = 0; gs < 4; ++gs) {
            const int sr = gs * Hd + er;
            #pragma unroll
            for (int s = 0; s < 2; ++s)
                #pragma unroll
                for (int e = 0; e < 8; ++e) {
                    const int kk = 32 * s + 8 * kg + e;
                    float v = 0.f;
                    if (rvalid) {
                        if (kk < 51)                   v = Whh0[sr * 51 + kk];
                        else if (kk == 52 || kk == 53) v = Wih0[sr * 2 + (kk - 52)];
                        else if (kk == 54)             v = bih0[sr] + bhh0[sr];
                    }
                    AF[gs * 2 + s][e] = (_Float16)v;
                }
            #pragma unroll
            for (int s = 0; s < 4; ++s)
                #pragma unroll
                for (int e = 0; e < 8; ++e) {
                    const int kk = 32 * s + 8 * kg + e;
                    float v = 0.f;
                    if (rvalid) {
                        if (kk < 51)                   v = Wih1[sr * 51 + kk];
                        else if (kk >= 56 && kk < 107) v = Whh1[sr * 51 + (kk - 56)];
                        else if (kk == 112)            v = bih1[sr] + bhh1[sr];
                    }
                    AF[8 + gs * 4 + s][e] = (_Float16)v;
                }
        }
    } else {
        #pragma unroll
        for (int gs = 0; gs < 4; ++gs) {
            const int sr = gs * Hd + er;
            #pragma unroll
            for (int s = 0; s < 4; ++s)
                #pragma unroll
                for (int e = 0; e < 8; ++e) {
                    const int kk = 32 * s + 8 * kg + e;
                    float v = 0.f;
                    if (rvalid) {
                        if (kk < 51)                   v = Wih2[sr * 51 + kk];
                        else if (kk >= 56 && kk < 107) v = Whh2[sr * 51 + (kk - 56)];
                        else if (kk == 112)            v = bih2[sr] + bhh2[sr];
                    } else if (gs == 0 && (er == 52 || er == 53)) {
                        const int hr = er - 52;        // head rows: W_lin embedded
                        if (kk >= 56 && kk < 107)      v = Wlin[hr * 51 + (kk - 56)];
                        else if (kk == 112)            v = blin[hr];
                    }
                    AF[gs * 4 + s][e] = (_Float16)v;
                }
        }
    }

    float cs[8];
    #pragma unroll
    for (int i = 0; i < 8; ++i) cs[i] = 0.f;
    float (&cs_a)[4] = *(float(*)[4])&cs[0];
    float (&cs_b)[4] = *(float(*)[4])&cs[4];

    const int e0 = 16 * c + 4 * kg;   // first element of this lane's 4 C rows
    const bool wr_ok = (e0 < Hd);     // guard: never touch x/one/pad slots
    const f32x4 Z = {0.f, 0.f, 0.f, 0.f};

    __syncthreads();

    // layer skew: iter n computes L0@t=n, L1@t=n-1, L2@t=n-2, head@t=n-3
    for (int n = 0; n <= Td + 2; ++n) {
        const int rb = n & 1, wb = rb ^ 1;

        if (low) {
            if (n < Td) {  // ---- L0 ----
                f16x8 B0h = *(const f16x8*)(lds + vaddr(BASE0, RB0, rb, 0, ncol, 16 * kg));
                f16x8 B1h = *(const f16x8*)(lds + vaddr(BASE0, RB0, rb, 0, ncol, 64 + 16 * kg));
                f16x8 B0l = *(const f16x8*)(lds + vaddr(BASE0, RB0, rb, 1, ncol, 16 * kg));
                f16x8 B1l = *(const f16x8*)(lds + vaddr(BASE0, RB0, rb, 1, ncol, 64 + 16 * kg));
                f32x4 acc[4] = {Z, Z, Z, Z};
                #pragma unroll
                for (int gs = 0; gs < 4; ++gs) {
                    acc[gs] = __builtin_amdgcn_mfma_f32_16x16x32_f16(AF[gs * 2 + 0], B0h, acc[gs], 0, 0, 0);
                    acc[gs] = __builtin_amdgcn_mfma_f32_16x16x32_f16(AF[gs * 2 + 0], B0l, acc[gs], 0, 0, 0);
                    acc[gs] = __builtin_amdgcn_mfma_f32_16x16x32_f16(AF[gs * 2 + 1], B1h, acc[gs], 0, 0, 0);
                    acc[gs] = __builtin_amdgcn_mfma_f32_16x16x32_f16(AF[gs * 2 + 1], B1l, acc[gs], 0, 0, 0);
                }
                if (wr_ok)
                    update_write(lds, acc, cs_a,
                                 vaddr(BASE0, RB0,  wb, 0, ncol, 2 * e0), RB0,
                                 vaddr(BASE1, RB12, wb, 0, ncol, 2 * e0), RB12);
            }
            if (n >= 1 && n <= Td) {  // ---- L1 ----
                f16x8 Bh[4], Bl[4];
                #pragma unroll
                for (int s = 0; s < 4; ++s) {
                    Bh[s] = *(const f16x8*)(lds + vaddr(BASE1, RB12, rb, 0, ncol, 64 * s + 16 * kg));
                    Bl[s] = *(const f16x8*)(lds + vaddr(BASE1, RB12, rb, 1, ncol, 64 * s + 16 * kg));
                }
                f32x4 acc[4] = {Z, Z, Z, Z};
                #pragma unroll
                for (int s = 0; s < 4; ++s)
                    #pragma unroll
                    for (int gs = 0; gs < 4; ++gs) {
                        acc[gs] = __builtin_amdgcn_mfma_f32_16x16x32_f16(AF[8 + gs * 4 + s], Bh[s], acc[gs], 0, 0, 0);
                        acc[gs] = __builtin_amdgcn_mfma_f32_16x16x32_f16(AF[8 + gs * 4 + s], Bl[s], acc[gs], 0, 0, 0);
                    }
                if (wr_ok)
                    update_write(lds, acc, cs_b,
                                 vaddr(BASE1, RB12, wb, 0, ncol, 112 + 2 * e0), RB12,
                                 vaddr(BASE2, RB12, wb, 0, ncol, 2 * e0), RB12);
            }
        } else {
            if (n >= 2) {  // ---- L2 (+head rows 52,53 inside gs=0 tiles) ----
                f16x8 Bh[4], Bl[4];
                #pragma unroll
                for (int s = 0; s < 4; ++s) {
                    Bh[s] = *(const f16x8*)(lds + vaddr(BASE2, RB12, rb, 0, ncol, 64 * s + 16 * kg));
                    Bl[s] = *(const f16x8*)(lds + vaddr(BASE2, RB12, rb, 1, ncol, 64 * s + 16 * kg));
                }
                f32x4 acc[4] = {Z, Z, Z, Z};
                #pragma unroll
                for (int s = 0; s < 4; ++s)
                    #pragma unroll
                    for (int gs = 0; gs < 4; ++gs) {
                        acc[gs] = __builtin_amdgcn_mfma_f32_16x16x32_f16(AF[gs * 4 + s], Bh[s], acc[gs], 0, 0, 0);
                        acc[gs] = __builtin_amdgcn_mfma_f32_16x16x32_f16(AF[gs * 4 + s], Bl[s], acc[gs], 0, 0, 0);
                    }
                if (n <= Td + 1 && wr_ok)
                    update_write(lds, acc, cs_a,
                                 vaddr(BASE2, RB12, wb, 0, ncol, 112 + 2 * e0), RB12,
                                 -1, 0);
                if (w == 7 && kg == 1 && n >= 3) {
                    // head rows 52,53 -> tile c=3, C rows 4,5 -> kg=1, regs 0,1
                    float mean = acc[0][0];
                    float spre = acc[0][1];
                    float sp = (spre > 30.f) ? spre : __logf(1.f + __expf(spre));
                    const int t = n - 3;
                    float2 o2 = make_float2(mean, sp);
                    *(float2*)&g_out[((size_t)(b0 + ncol) * Td + t) * 2] = o2;
                }
            }
            if (w == 4 && lane < 32 && (n + 1) < Td) {  // x prefetch for L0@t=n+1
                int nb = lane & 15, f = (lane >> 4) & 1;
                const float* src = f ? g_time : g_input;
                float v = src[(size_t)(b0 + nb) * Td + (n + 1)];
                _Float16 hi = (_Float16)v;
                *(_Float16*)(lds + vaddr(BASE0, RB0, wb, 0, nb, (52 + f) * 2)) = hi;
                *(_Float16*)(lds + vaddr(BASE0, RB0, wb, 1, nb, (52 + f) * 2)) = (_Float16)(v - (float)hi);
            }
        }
        __syncthreads();  // single barrier: wb writes become next iter's rb reads
    }
}

extern "C" void kernel_launch(void* const* d_in, const int* in_sizes, int n_in,
                              void* d_out, int out_size, void* d_ws, size_t ws_size,
                              hipStream_t stream) {
    const float* input = (const float*)d_in[0];
    const float* timei = (const float*)d_in[1];
    const float* Wih0  = (const float*)d_in[2];
    const float* Whh0  = (const float*)d_in[3];
    const float* bih0  = (const float*)d_in[4];
    const float* bhh0  = (const float*)d_in[5];
    const float* Wih1  = (const float*)d_in[6];
    const float* Whh1  = (const float*)d_in[7];
    const float* bih1  = (const float*)d_in[8];
    const float* bhh1  = (const float*)d_in[9];
    const float* Wih2  = (const float*)d_in[10];
    const float* Whh2  = (const float*)d_in[11];
    const float* bih2  = (const float*)d_in[12];
    const float* bhh2  = (const float*)d_in[13];
    const float* Wlin  = (const float*)d_in[14];
    const float* blin  = (const float*)d_in[15];
    float* out = (float*)d_out;

    lstm3_mfma<<<dim3(NBLK), dim3(NTH), 0, stream>>>(
        input, timei,
        Wih0, Whh0, bih0, bhh0,
        Wih1, Whh1, bih1, bhh1,
        Wih2, Whh2, bih2, bhh2,
        Wlin, blin, out);
}